// Round 1
// baseline (309.107 us; speedup 1.0000x reference)
//
#include <hip/hip_runtime.h>

// FractalEmbedding: out[b,l,d] = scale * sum_f feats(token)[f] * W[d,f]
// feats = 8-step Julia iteration on c_table[token], interleaved (zr,zi).
//
// B=8, L=8192 -> 65536 tokens; D=1024; 2*STEPS=16 features.
// Output = 268 MB f32 -> write-BW bound. Strategy: W rows live in registers
// (thread t owns dims 4t..4t+3 => 64 floats), feats computed redundantly per
// thread (cheap), float4 coalesced stores, grid-stride over tokens.

#define STEPS 8
#define NFEAT (2 * STEPS)
#define EMBED 1024
#define NTOK (8 * 8192)
#define BLOCK 256
#define GRID 2048

__global__ __launch_bounds__(BLOCK) void FractalEmbedding_30365418782757_kernel(
    const int* __restrict__ tok,
    const float* __restrict__ ctab,   // (V, 2)
    const float* __restrict__ W,      // (1024, 16) row-major
    const float* __restrict__ scale_p,
    float* __restrict__ out)          // (NTOK, 1024)
{
    const int t = threadIdx.x;  // thread t -> output dims 4t .. 4t+3

    // Load this thread's 4 W rows into registers (64 floats).
    float w[4][NFEAT];
#pragma unroll
    for (int r = 0; r < 4; ++r) {
        const float4* wrow = reinterpret_cast<const float4*>(W + (size_t)(4 * t + r) * NFEAT);
#pragma unroll
        for (int q = 0; q < 4; ++q) {
            float4 v = wrow[q];
            w[r][4 * q + 0] = v.x;
            w[r][4 * q + 1] = v.y;
            w[r][4 * q + 2] = v.z;
            w[r][4 * q + 3] = v.w;
        }
    }
    const float s = *scale_p;

    for (int ti = blockIdx.x; ti < NTOK; ti += gridDim.x) {
        const int id = tok[ti];                                   // wave-uniform
        const float2 c = reinterpret_cast<const float2*>(ctab)[id]; // broadcast load

        // 8-step Julia recurrence, f32 exactly like the reference.
        float f[NFEAT];
        float zr = 0.0f, zi = 0.0f;
#pragma unroll
        for (int st = 0; st < STEPS; ++st) {
            float nzr = zr * zr - zi * zi + c.x;
            float nzi = 2.0f * zr * zi + c.y;
            zr = nzr;
            zi = nzi;
            f[2 * st]     = zr;
            f[2 * st + 1] = zi;
        }

        // 4 output dims: dot(feats, w[r]) * scale
        float4 o;
        float* op = &o.x;
#pragma unroll
        for (int r = 0; r < 4; ++r) {
            float acc = 0.0f;
#pragma unroll
            for (int k = 0; k < NFEAT; ++k) acc += f[k] * w[r][k];
            op[r] = acc * s;
        }
        reinterpret_cast<float4*>(out + (size_t)ti * EMBED)[t] = o;  // 4 KB/block/token, coalesced
    }
}

extern "C" void kernel_launch(void* const* d_in, const int* in_sizes, int n_in,
                              void* d_out, int out_size, void* d_ws, size_t ws_size,
                              hipStream_t stream) {
    const int*   tok   = (const int*)d_in[0];
    const float* ctab  = (const float*)d_in[1];
    const float* W     = (const float*)d_in[2];
    const float* scale = (const float*)d_in[3];
    float*       out   = (float*)d_out;

    FractalEmbedding_30365418782757_kernel<<<GRID, BLOCK, 0, stream>>>(tok, ctab, W, scale, out);
}